// Round 10
// baseline (395.604 us; speedup 1.0000x reference)
//
#include <hip/hip_runtime.h>

#define TLEN  4096
#define NROWS 4096
#define RPB   32            // rows per block (owned by the scan wave)
#define K     32            // timesteps per chunk
#define NC    (TLEN / K)    // 128 chunks
#define SGSL  (2 * 16 * 32) // coef slot: 2 dir-regions x 16 tp x 32 rows (float4 units)
#define DIRS  (16 * 32)     // dir-region stride inside a slot (float4 units, 8 KB)
#define STP   34            // staging pitch (dwords): 32 steps + 2 pad (r6-proven, 0 conflicts)
#define STSL  (64 * STP)    // output-staging slot (floats)
#define UN    8             // exact-path unroll

__device__ __forceinline__ float fexp2(float x) { return __builtin_amdgcn_exp2f(x); }
__device__ __forceinline__ float frcp(float x)  { return __builtin_amdgcn_rcpf(x); }
__device__ __forceinline__ float sigz(float z)  { return frcp(1.0f + fexp2(z)); }

// Swap adjacent lanes (lane ^ 1): DPP quad_perm [1,0,3,2].
__device__ __forceinline__ float lane_swap1(float v) {
    int r = __builtin_amdgcn_update_dpp(0, __float_as_int(v), 0xB1, 0xF, 0xF, true);
    return __int_as_float(r);
}

// ---------------------------------------------------------------------------
// Round-10 = round-9 structure (184us, best measured; helper hidden) + two
// scan-stream cuts, each proven separately, now with conflict-free layouts:
//   (1) premultiplied input coefs (r4 math): scan does m = fma(a,x,b) where
//       a = GnA*sgin, b = PA*sgin come from the helper. -1 slot/step AND the
//       x-chain shortens 5 -> 4 FMAs. r4's mistake was its stride-2 coef
//       write (2.1M conflicts); fixed by DIR-SPLIT regions: x-coefs and
//       y-coefs live in separate 8KB-apart LDS regions. Helper writes each
//       region as contiguous-per-32-lane b128 runs (2-way alias = free);
//       scan even/odd lanes read their own region at [tp*32+row] (2-way).
//   (2) r6's staging: per-lane contiguous [64][34] rows, ONE ds_write_b64
//       per step-pair (-0.5 slot/step); r6 measured 0 conflicts. Flush
//       transposes on the helper side (hidden).
//   (3) u-refresh once per pair (r6-validated numerics, -0.5 slot/step).
// Scan: ~11.3 slots/step vs r9's ~13. Deg-1 sigma-Taylor, exact resync
// every 16 steps (r8/r9-validated: absmax 0.00390625 reproduced).
// ---------------------------------------------------------------------------
__device__ void run_fast(const float* __restrict__ inp, const float* __restrict__ prm,
                         float* __restrict__ out,
                         float4* __restrict__ sgbuf,  // [2 slot][2 dir][16 tp][32 row]
                         float*  __restrict__ st) {   // [2 slot][64 lane][STP]
    const int tid  = threadIdx.x;
    const int wid  = tid >> 6;          // 0 = scan wave, 1 = helper wave
    const int lane = tid & 63;
    const int R0   = blockIdx.x * RPB;
    const float L2E = 1.4426950408889634f;
    float2* __restrict__ out2 = (float2*)out;

    if (wid == 1) {
        // ---------------- helper wave ----------------
        const int r = lane & 31, h = lane >> 5;
        // input-dir constants: 'ax' (base 2) for x, 'by' (base 6) for y
        const float c1x = -prm[4] * L2E, c0x = prm[4] * prm[3] * L2E;
        const float c1y = -prm[8] * L2E, c0y = prm[8] * prm[7] * L2E;
        const float gAx = prm[2] / prm[0], PAx = gAx * prm[5], GnAx = -gAx;
        const float gAy = prm[6] / prm[1], PAy = gAy * prm[9], GnAy = -gAy;
        const float4* __restrict__ src = (const float4*)inp + (size_t)(R0 + r) * (TLEN / 2);

        float4 bufA[8], bufB[8];

        auto produce_reg = [&](const float4* buf, int c) {  // regs -> coef slot c&1
            float4* slX = sgbuf + ((c & 1) ? SGSL : 0);
            float4* slY = slX + DIRS;
#pragma unroll
            for (int j = 0; j < 8; ++j) {
                const int tp = h * 8 + j;
                float4 v = buf[j];            // (a_t, b_t, a_t+1, b_t+1)
                float sx0 = sigz(__builtin_fmaf(c1x, v.x, c0x));
                float sy0 = sigz(__builtin_fmaf(c1y, v.y, c0y));
                float sx1 = sigz(__builtin_fmaf(c1x, v.z, c0x));
                float sy1 = sigz(__builtin_fmaf(c1y, v.w, c0y));
                float4 ox; ox.x = GnAx * sx0; ox.y = PAx * sx0;
                           ox.z = GnAx * sx1; ox.w = PAx * sx1;
                float4 oy; oy.x = GnAy * sy0; oy.y = PAy * sy0;
                           oy.z = GnAy * sy1; oy.w = PAy * sy1;
                slX[tp * 32 + r] = ox;        // contiguous per 32-lane group: free
                slY[tp * 32 + r] = oy;
            }
        };
        auto flush = [&](int c) {     // st slot c&1 -> out, 256B coalesced runs
            const float* sl = st + ((c & 1) ? STSL : 0);
            const int col = lane & 31;
#pragma unroll
            for (int j = 0; j < 16; ++j) {
                int ro = 2 * j + (lane >> 5);
                float2 v;
                v.x = sl[(2 * ro)     * STP + col];  // x of row ro, step col
                v.y = sl[(2 * ro + 1) * STP + col];  // y of row ro, step col
                out2[(size_t)(R0 + ro) * TLEN + (size_t)c * K + col] = v;
            }
        };

        // prologue: chunk 0 -> bufA -> produce; chunk 1 -> bufB (in flight)
#pragma unroll
        for (int j = 0; j < 8; ++j) bufA[j] = src[h * 8 + j];
        produce_reg(bufA, 0);
#pragma unroll
        for (int j = 0; j < 8; ++j) bufB[j] = src[16 + h * 8 + j];
        __syncthreads();                       // slot 0 ready for scan
        for (int c = 0; c < NC; ++c) {
            if ((c & 1) == 0) {
                if (c + 1 < NC) produce_reg(bufB, c + 1);   // chunk c+1 (odd)
                if (c + 2 < NC) {
#pragma unroll
                    for (int j = 0; j < 8; ++j)
                        bufA[j] = src[(c + 2) * 16 + h * 8 + j];
                }
            } else {
                if (c + 1 < NC) produce_reg(bufA, c + 1);   // chunk c+1 (even)
                if (c + 2 < NC) {
#pragma unroll
                    for (int j = 0; j < 8; ++j)
                        bufB[j] = src[(c + 2) * 16 + h * 8 + j];
                }
            }
            if (c >= 1) flush(c - 1);          // previous chunk's outputs
            __syncthreads();
        }
        flush(NC - 1);                         // epilogue: last chunk's outputs
    } else {
        // ---------------- scan wave ----------------
        // Lane pair (2r, 2r+1) owns row r: even lane = x, odd = y.
        const int r_  = lane >> 1;
        const int par = lane & 1;
        const int sfB = par ? 22 : 18, t2B = par ? 10 : 14;
        const float ic  = 1.0f / prm[par];
        const float g1  = prm[sfB] * ic, P1 = g1 * prm[sfB + 3], Gn1 = -g1; // self
        const float g2  = prm[t2B] * ic, P2 = g2 * prm[t2B + 3], Gn2 = -g2; // cross
        const float sdz = prm[sfB + 2];
        const float c1s = -sdz * L2E, c0s = sdz * prm[sfB + 1] * L2E;

        float x   = par ? 1.0f : 0.0f;
        float sig = sigz(__builtin_fmaf(c1s, x, c0s));
        float u   = __builtin_fmaf(-sig, sig, sig);   // sig*(1-sig)

        auto resync = [&]() {                         // exact sigma (off-chain)
            sig = sigz(__builtin_fmaf(c1s, x, c0s));
            u   = __builtin_fmaf(-sig, sig, sig);
        };

        __syncthreads();                       // coef slot 0 ready
        for (int c = 0; c < NC; ++c) {
            // this lane's dir-region: even -> X, odd -> Y (regions 8 KB apart
            // => identical bank alignment => pair reads are 2-way = free)
            const float4* lb = sgbuf + ((c & 1) ? SGSL : 0) + par * DIRS;
            float* wp = st + ((c & 1) ? STSL : 0) + lane * STP;
            float4 f0 = lb[r_];
            float4 f1 = lb[32 + r_];
#pragma unroll
            for (int tp = 0; tp < 16; ++tp) {
                float4 f = f0; f0 = f1;
                if (tp < 14) f1 = lb[(tp + 2) * 32 + r_];   // 2-granule lookahead
                // step A: coefs (f.x = GnA*sgin, f.y = PA*sgin)
                float m1  = __builtin_fmaf(f.x, x, f.y);
                float t1v = __builtin_fmaf(Gn1, x, P1);
                float t2v = __builtin_fmaf(Gn2, x, P2);
                float b21 = __builtin_fmaf(sig, t1v, m1);
                float sc1 = lane_swap1(sig);
                float dxa = __builtin_fmaf(sc1, t2v, b21);
                x = x + dxa;
                float xa  = x;
                float dza = sdz * dxa;
                sig = __builtin_fmaf(u, dza, sig);          // deg-1 Taylor
                // step B: coefs (f.z, f.w)
                float m2   = __builtin_fmaf(f.z, x, f.w);
                float t1v2 = __builtin_fmaf(Gn1, x, P1);
                float t2v2 = __builtin_fmaf(Gn2, x, P2);
                float b22  = __builtin_fmaf(sig, t1v2, m2);
                float sc2  = lane_swap1(sig);
                float dxb  = __builtin_fmaf(sc2, t2v2, b22);
                x = x + dxb;
                float dzb = sdz * dxb;
                sig = __builtin_fmaf(u, dzb, sig);          // deg-1 Taylor
                u   = __builtin_fmaf(-sig, sig, sig);       // refresh once / pair
                float2 w2; w2.x = xa; w2.y = x;
                *(float2*)(wp + 2 * tp) = w2;               // ds_write_b64
                if (tp == 7) resync();                      // mid-chunk resync
            }
            resync();                                       // end-chunk resync
            __syncthreads();                   // hand slots to helper / get next
        }
    }
}

// ---------------------------------------------------------------------------
// Exact fallback for general params (proven path; 128-thr blocks cover all
// 8192 lanes).
// ---------------------------------------------------------------------------
struct LaneConst {
    float c1_in, c0_in, c1_sf, c0_sf, c1_ot, c0_ot;
    float gS_in, gS_cr, gS_sf, gP_in, gP_cr, gP_sf;
};

__device__ __forceinline__ float do_step_exact(float s, float pre_in, const LaneConst& k) {
    float sig_in = sigz(__builtin_fmaf(k.c1_in, pre_in, k.c0_in));
    float sig_sf = sigz(__builtin_fmaf(k.c1_sf, s, k.c0_sf));
    float sig_ot = sigz(__builtin_fmaf(k.c1_ot, s, k.c0_ot));
    float sig_cr = lane_swap1(sig_ot);
    float S = __builtin_fmaf(k.gS_in, sig_in, __builtin_fmaf(k.gS_cr, sig_cr, k.gS_sf * sig_sf));
    float P = __builtin_fmaf(k.gP_in, sig_in, __builtin_fmaf(k.gP_cr, sig_cr, k.gP_sf * sig_sf));
    return s + __builtin_fmaf(S, -s, P);
}

__device__ void run_exact(const float* __restrict__ inp, const float* __restrict__ prm,
                          float* __restrict__ out) {
    const int tid = blockIdx.x * 128 + threadIdx.x;
    const int row = tid >> 1;
    if (row >= NROWS) return;
    const int par = tid & 1;
    const float L2E = 1.4426950408889634f;
    const int inB = par ? 6 : 2, sfB = par ? 22 : 18, otB = par ? 14 : 10, crB = par ? 10 : 14;
    const float invc = 1.0f / prm[par];
    LaneConst k;
    float sd = prm[inB + 2], mn = prm[inB + 1];
    k.c1_in = -sd * L2E; k.c0_in = sd * mn * L2E;
    sd = prm[sfB + 2]; mn = prm[sfB + 1];
    k.c1_sf = -sd * L2E; k.c0_sf = sd * mn * L2E;
    sd = prm[otB + 2]; mn = prm[otB + 1];
    k.c1_ot = -sd * L2E; k.c0_ot = sd * mn * L2E;
    k.gS_in = prm[inB] * invc; k.gP_in = k.gS_in * prm[inB + 3];
    k.gS_sf = prm[sfB] * invc; k.gP_sf = k.gS_sf * prm[sfB + 3];
    k.gS_cr = prm[crB] * invc; k.gP_cr = k.gS_cr * prm[crB + 3];

    const float4* __restrict__ src = (const float4*)inp + (size_t)row * (TLEN / 2);
    float* __restrict__ dst = out + (size_t)row * (TLEN * 2) + par;
    float s = par ? 1.0f : 0.0f;

    float4 cur[UN], nxt[UN];
#pragma unroll
    for (int j = 0; j < UN; ++j) cur[j] = src[j];
    const int NIT = TLEN / (2 * UN);
    for (int it = 0; it < NIT; ++it) {
        if (it + 1 < NIT) {
#pragma unroll
            for (int j = 0; j < UN; ++j) nxt[j] = src[(it + 1) * UN + j];
        }
        float* dptr = dst + it * (UN * 4);
#pragma unroll
        for (int j = 0; j < UN; ++j) {
            float4 f = cur[j];
            s = do_step_exact(s, par ? f.y : f.x, k);
            dptr[j * 4] = s;
            s = do_step_exact(s, par ? f.w : f.z, k);
            dptr[j * 4 + 2] = s;
        }
#pragma unroll
        for (int j = 0; j < UN; ++j) cur[j] = nxt[j];
    }
}

__global__ __launch_bounds__(128, 1)
void memcell_scan(const float* __restrict__ inp, const float* __restrict__ prm,
                  float* __restrict__ out) {
    __shared__ float4 sgbuf[2 * SGSL];   // 32 KB coef double-buffer (dir-split)
    __shared__ float  st[2 * STSL];      // 17.4 KB output staging double-buffer

    // Fast-path guard:
    //  - shared (mean,std) between self & cross state dirs (xx==xy, yy==yx)
    //  - g >= 0, caps > 0         -> states stay in hull{s0, pots}
    //  - sum(g/cap) <= 0.25       -> no overshoot
    //  - wb = std*max|dx| <= 0.02 -> deg-1 sigma-Taylor valid
    //    (exact resync every 16 steps bounds drift to ~1e-4)
    //  - |z| <= 20                -> sigz well-conditioned
    const bool shared = (prm[11] == prm[19]) && (prm[12] == prm[20]) &&
                        (prm[15] == prm[23]) && (prm[16] == prm[24]);
    const float capx = prm[0], capy = prm[1];
    const bool gpos = prm[2] >= 0.f && prm[6] >= 0.f && prm[10] >= 0.f &&
                      prm[14] >= 0.f && prm[18] >= 0.f && prm[22] >= 0.f &&
                      capx > 0.f && capy > 0.f;
    const float sx = (prm[2] + prm[14] + prm[18]) / capx;
    const float sy = (prm[6] + prm[10] + prm[22]) / capy;
    const float lox = fminf(0.f, fminf(prm[5], fminf(prm[17], prm[21])));
    const float hix = fmaxf(0.f, fmaxf(prm[5], fmaxf(prm[17], prm[21])));
    const float loy = fminf(1.f, fminf(prm[9], fminf(prm[13], prm[25])));
    const float hiy = fmaxf(1.f, fmaxf(prm[9], fmaxf(prm[13], prm[25])));
    const float wbx = prm[20] * sx * (hix - lox), wby = prm[24] * sy * (hiy - loy);
    const float zmx = prm[20] * fmaxf(fabsf(lox - prm[19]), fabsf(hix - prm[19]));
    const float zmy = prm[24] * fmaxf(fabsf(loy - prm[23]), fabsf(hiy - prm[23]));
    const bool fast = shared && gpos && sx <= 0.25f && sy <= 0.25f &&
                      wbx <= 0.02f && wby <= 0.02f && zmx <= 20.f && zmy <= 20.f;
    if (fast) {
        run_fast(inp, prm, out, sgbuf, st);
    } else {
        run_exact(inp, prm, out);
    }
}

extern "C" void kernel_launch(void* const* d_in, const int* in_sizes, int n_in,
                              void* d_out, int out_size, void* d_ws, size_t ws_size,
                              hipStream_t stream) {
    (void)in_sizes; (void)n_in; (void)d_ws; (void)ws_size; (void)out_size;
    const float* inp = (const float*)d_in[0];
    const float* prm = (const float*)d_in[1];
    float* out = (float*)d_out;
    memcell_scan<<<dim3(NROWS / RPB), dim3(128), 0, stream>>>(inp, prm, out);
}

// Round 11
// 395.498 us; speedup vs baseline: 1.0003x; 1.0003x over previous
//
#include <hip/hip_runtime.h>

#define TLEN  4096
#define NROWS 4096
#define RPB   32            // rows per block (owned by the scan wave)
#define K     32            // timesteps per chunk
#define NC    (TLEN / K)    // 128 chunks
#define SGSL  (32 * 32)     // coef slot: 32 steps x 32 rows (float4 units) = 16 KB
#define STP   34            // staging pitch (dwords): 32 steps + 2 pad (r6-proven, 0 conflicts)
#define STSL  (64 * STP)    // output-staging slot (floats)
#define UN    8             // exact-path unroll

__device__ __forceinline__ float fexp2(float x) { return __builtin_amdgcn_exp2f(x); }
__device__ __forceinline__ float frcp(float x)  { return __builtin_amdgcn_rcpf(x); }
__device__ __forceinline__ float sigz(float z)  { return frcp(1.0f + fexp2(z)); }

// Swap adjacent lanes (lane ^ 1): DPP quad_perm [1,0,3,2].
__device__ __forceinline__ float lane_swap1(float v) {
    int r = __builtin_amdgcn_update_dpp(0, __float_as_int(v), 0xB1, 0xF, 0xF, true);
    return __int_as_float(r);
}

// ---------------------------------------------------------------------------
// Round-11 = round-9 base (184us, verified) + premultiplied coefs with a
// bank-clean layout + two r6-proven cuts. r10 lesson: r9's pair-BROADCAST
// b128 coef read was conflict-free by quarter-wave construction; the
// dir-split de-broadcast went 2-way per quarter on b128 (+1.05M conflicts,
// +29cyc/step). This round's layout is clean by construction WITHOUT
// broadcast:
//   coef slot [32 t][32 row] float4 = (Gnx*sgx, Px*sgx, Gny*sgy, Py*sgy).
//   Scan lane 2r does ds_read_b64 of bytes [0,8) of [t][r]; lane 2r+1 reads
//   [8,16). Quarter-wave (8 pairs): banks {4r..4r+3} -> 0..31 exactly once.
//   No divergent dir-select, 2 b64 reads per step-pair.
// Scan step (premult coefs, m = fma(a,x,b)):
//   m, t1v, t2v, b2, DPP, dx, x+=, sig=fma(u',dx,sig)  = 8 slots
// per pair: + u' = sdz*(sig-sig^2) refresh (2) + one ds_write_b64 staging
// ([64][34], r6-proven) + 2 reads ~= 22.5 slots/pair = 11.25/step vs r9 ~13.
// Deg-1 sigma-Taylor, exact resync every 16 steps (r8-r10 validated).
// ---------------------------------------------------------------------------
__device__ void run_fast(const float* __restrict__ inp, const float* __restrict__ prm,
                         float* __restrict__ out,
                         float4* __restrict__ sgbuf,  // [2 slot][32 t][32 row]
                         float*  __restrict__ st) {   // [2 slot][64 lane][STP]
    const int tid  = threadIdx.x;
    const int wid  = tid >> 6;          // 0 = scan wave, 1 = helper wave
    const int lane = tid & 63;
    const int R0   = blockIdx.x * RPB;
    const float L2E = 1.4426950408889634f;
    float2* __restrict__ out2 = (float2*)out;

    if (wid == 1) {
        // ---------------- helper wave ----------------
        const int r = lane & 31, h = lane >> 5;
        // input-dir constants: 'ax' (base 2) for x, 'by' (base 6) for y
        const float c1x = -prm[4] * L2E, c0x = prm[4] * prm[3] * L2E;
        const float c1y = -prm[8] * L2E, c0y = prm[8] * prm[7] * L2E;
        const float gAx = prm[2] / prm[0], PAx = gAx * prm[5], GnAx = -gAx;
        const float gAy = prm[6] / prm[1], PAy = gAy * prm[9], GnAy = -gAy;
        const float4* __restrict__ src = (const float4*)inp + (size_t)(R0 + r) * (TLEN / 2);

        float4 bufA[8], bufB[8];

        auto produce_reg = [&](const float4* buf, int c) {  // regs -> coef slot c&1
            float4* sl = sgbuf + ((c & 1) ? SGSL : 0);
#pragma unroll
            for (int j = 0; j < 8; ++j) {
                const int t0 = 2 * (h * 8 + j);
                float4 v = buf[j];            // (a_t, b_t, a_t+1, b_t+1)
                float sx0 = sigz(__builtin_fmaf(c1x, v.x, c0x));
                float sy0 = sigz(__builtin_fmaf(c1y, v.y, c0y));
                float sx1 = sigz(__builtin_fmaf(c1x, v.z, c0x));
                float sy1 = sigz(__builtin_fmaf(c1y, v.w, c0y));
                float4 o0; o0.x = GnAx * sx0; o0.y = PAx * sx0;
                           o0.z = GnAy * sy0; o0.w = PAy * sy0;
                float4 o1; o1.x = GnAx * sx1; o1.y = PAx * sx1;
                           o1.z = GnAy * sy1; o1.w = PAy * sy1;
                // per-quarter banks: r*4..r*4+3 -> 2-way max (r9-verified write)
                sl[t0 * 32 + r]       = o0;
                sl[(t0 + 1) * 32 + r] = o1;
            }
        };
        auto flush = [&](int c) {     // st slot c&1 -> out, 256B coalesced runs
            const float* sl = st + ((c & 1) ? STSL : 0);
            const int col = lane & 31;
#pragma unroll
            for (int j = 0; j < 16; ++j) {
                int ro = 2 * j + (lane >> 5);
                float2 v;
                v.x = sl[(2 * ro)     * STP + col];  // x of row ro, step col
                v.y = sl[(2 * ro + 1) * STP + col];  // y of row ro, step col
                out2[(size_t)(R0 + ro) * TLEN + (size_t)c * K + col] = v;
            }
        };

        // prologue: chunk 0 -> bufA -> produce; chunk 1 -> bufB (in flight)
#pragma unroll
        for (int j = 0; j < 8; ++j) bufA[j] = src[h * 8 + j];
        produce_reg(bufA, 0);
#pragma unroll
        for (int j = 0; j < 8; ++j) bufB[j] = src[16 + h * 8 + j];
        __syncthreads();                       // slot 0 ready for scan
        for (int c = 0; c < NC; ++c) {
            if ((c & 1) == 0) {
                if (c + 1 < NC) produce_reg(bufB, c + 1);   // chunk c+1 (odd)
                if (c + 2 < NC) {
#pragma unroll
                    for (int j = 0; j < 8; ++j)
                        bufA[j] = src[(c + 2) * 16 + h * 8 + j];
                }
            } else {
                if (c + 1 < NC) produce_reg(bufA, c + 1);   // chunk c+1 (even)
                if (c + 2 < NC) {
#pragma unroll
                    for (int j = 0; j < 8; ++j)
                        bufB[j] = src[(c + 2) * 16 + h * 8 + j];
                }
            }
            if (c >= 1) flush(c - 1);          // previous chunk's outputs
            __syncthreads();
        }
        flush(NC - 1);                         // epilogue: last chunk's outputs
    } else {
        // ---------------- scan wave ----------------
        // Lane pair (2r, 2r+1) owns row r: even lane = x, odd = y.
        const int r_  = lane >> 1;
        const int par = lane & 1;
        const int sfB = par ? 22 : 18, t2B = par ? 10 : 14;
        const float ic  = 1.0f / prm[par];
        const float g1  = prm[sfB] * ic, P1 = g1 * prm[sfB + 3], Gn1 = -g1; // self
        const float g2  = prm[t2B] * ic, P2 = g2 * prm[t2B + 3], Gn2 = -g2; // cross
        const float sdz = prm[sfB + 2];
        const float c1s = -sdz * L2E, c0s = sdz * prm[sfB + 1] * L2E;

        float x   = par ? 1.0f : 0.0f;
        float sig = sigz(__builtin_fmaf(c1s, x, c0s));
        float up  = sdz * __builtin_fmaf(-sig, sig, sig);   // sdz * sig*(1-sig)

        auto resync = [&]() {                         // exact sigma (off-chain)
            sig = sigz(__builtin_fmaf(c1s, x, c0s));
            up  = sdz * __builtin_fmaf(-sig, sig, sig);
        };

        __syncthreads();                       // coef slot 0 ready
        for (int c = 0; c < NC; ++c) {
            // per-lane coef pointer: float index r_*4 + par*2 inside a t-row
            // of 128 floats; element t at cb[t*128]. Lane-pair banks tile
            // 0..31 exactly once per quarter-wave (see header comment).
            const float* cb = (const float*)(sgbuf + ((c & 1) ? SGSL : 0))
                            + r_ * 4 + par * 2;
            float* wp = st + ((c & 1) ? STSL : 0) + lane * STP;
            float2 c0 = *(const float2*)&cb[0 * 128];
            float2 c1 = *(const float2*)&cb[1 * 128];
            float2 n0 = *(const float2*)&cb[2 * 128];
            float2 n1 = *(const float2*)&cb[3 * 128];
#pragma unroll
            for (int tp = 0; tp < 16; ++tp) {
                float2 a0 = c0, a1 = c1;
                c0 = n0; c1 = n1;
                if (tp < 14) {                         // 2-pair lookahead
                    n0 = *(const float2*)&cb[(2 * tp + 4) * 128];
                    n1 = *(const float2*)&cb[(2 * tp + 5) * 128];
                }
                // step A: coefs a0 = (GnA*sgin, PA*sgin)
                float m1  = __builtin_fmaf(a0.x, x, a0.y);
                float t1v = __builtin_fmaf(Gn1, x, P1);
                float t2v = __builtin_fmaf(Gn2, x, P2);
                float b21 = __builtin_fmaf(sig, t1v, m1);
                float sc1 = lane_swap1(sig);
                float dxa = __builtin_fmaf(sc1, t2v, b21);
                x = x + dxa;
                float xa  = x;
                sig = __builtin_fmaf(up, dxa, sig);         // deg-1 Taylor
                // step B: coefs a1
                float m2   = __builtin_fmaf(a1.x, x, a1.y);
                float t1v2 = __builtin_fmaf(Gn1, x, P1);
                float t2v2 = __builtin_fmaf(Gn2, x, P2);
                float b22  = __builtin_fmaf(sig, t1v2, m2);
                float sc2  = lane_swap1(sig);
                float dxb  = __builtin_fmaf(sc2, t2v2, b22);
                x = x + dxb;
                sig = __builtin_fmaf(up, dxb, sig);         // deg-1 Taylor
                up  = sdz * __builtin_fmaf(-sig, sig, sig); // refresh once / pair
                float2 w2; w2.x = xa; w2.y = x;
                *(float2*)(wp + 2 * tp) = w2;               // ds_write_b64
                if (tp == 7) resync();                      // mid-chunk resync
            }
            resync();                                       // end-chunk resync
            __syncthreads();                   // hand slots to helper / get next
        }
    }
}

// ---------------------------------------------------------------------------
// Exact fallback for general params (proven path; 128-thr blocks cover all
// 8192 lanes).
// ---------------------------------------------------------------------------
struct LaneConst {
    float c1_in, c0_in, c1_sf, c0_sf, c1_ot, c0_ot;
    float gS_in, gS_cr, gS_sf, gP_in, gP_cr, gP_sf;
};

__device__ __forceinline__ float do_step_exact(float s, float pre_in, const LaneConst& k) {
    float sig_in = sigz(__builtin_fmaf(k.c1_in, pre_in, k.c0_in));
    float sig_sf = sigz(__builtin_fmaf(k.c1_sf, s, k.c0_sf));
    float sig_ot = sigz(__builtin_fmaf(k.c1_ot, s, k.c0_ot));
    float sig_cr = lane_swap1(sig_ot);
    float S = __builtin_fmaf(k.gS_in, sig_in, __builtin_fmaf(k.gS_cr, sig_cr, k.gS_sf * sig_sf));
    float P = __builtin_fmaf(k.gP_in, sig_in, __builtin_fmaf(k.gP_cr, sig_cr, k.gP_sf * sig_sf));
    return s + __builtin_fmaf(S, -s, P);
}

__device__ void run_exact(const float* __restrict__ inp, const float* __restrict__ prm,
                          float* __restrict__ out) {
    const int tid = blockIdx.x * 128 + threadIdx.x;
    const int row = tid >> 1;
    if (row >= NROWS) return;
    const int par = tid & 1;
    const float L2E = 1.4426950408889634f;
    const int inB = par ? 6 : 2, sfB = par ? 22 : 18, otB = par ? 14 : 10, crB = par ? 10 : 14;
    const float invc = 1.0f / prm[par];
    LaneConst k;
    float sd = prm[inB + 2], mn = prm[inB + 1];
    k.c1_in = -sd * L2E; k.c0_in = sd * mn * L2E;
    sd = prm[sfB + 2]; mn = prm[sfB + 1];
    k.c1_sf = -sd * L2E; k.c0_sf = sd * mn * L2E;
    sd = prm[otB + 2]; mn = prm[otB + 1];
    k.c1_ot = -sd * L2E; k.c0_ot = sd * mn * L2E;
    k.gS_in = prm[inB] * invc; k.gP_in = k.gS_in * prm[inB + 3];
    k.gS_sf = prm[sfB] * invc; k.gP_sf = k.gS_sf * prm[sfB + 3];
    k.gS_cr = prm[crB] * invc; k.gP_cr = k.gS_cr * prm[crB + 3];

    const float4* __restrict__ src = (const float4*)inp + (size_t)row * (TLEN / 2);
    float* __restrict__ dst = out + (size_t)row * (TLEN * 2) + par;
    float s = par ? 1.0f : 0.0f;

    float4 cur[UN], nxt[UN];
#pragma unroll
    for (int j = 0; j < UN; ++j) cur[j] = src[j];
    const int NIT = TLEN / (2 * UN);
    for (int it = 0; it < NIT; ++it) {
        if (it + 1 < NIT) {
#pragma unroll
            for (int j = 0; j < UN; ++j) nxt[j] = src[(it + 1) * UN + j];
        }
        float* dptr = dst + it * (UN * 4);
#pragma unroll
        for (int j = 0; j < UN; ++j) {
            float4 f = cur[j];
            s = do_step_exact(s, par ? f.y : f.x, k);
            dptr[j * 4] = s;
            s = do_step_exact(s, par ? f.w : f.z, k);
            dptr[j * 4 + 2] = s;
        }
#pragma unroll
        for (int j = 0; j < UN; ++j) cur[j] = nxt[j];
    }
}

__global__ __launch_bounds__(128, 1)
void memcell_scan(const float* __restrict__ inp, const float* __restrict__ prm,
                  float* __restrict__ out) {
    __shared__ float4 sgbuf[2 * SGSL];   // 32 KB coef double-buffer
    __shared__ float  st[2 * STSL];      // 17.4 KB output staging double-buffer

    // Fast-path guard:
    //  - shared (mean,std) between self & cross state dirs (xx==xy, yy==yx)
    //  - g >= 0, caps > 0         -> states stay in hull{s0, pots}
    //  - sum(g/cap) <= 0.25       -> no overshoot
    //  - wb = std*max|dx| <= 0.02 -> deg-1 sigma-Taylor valid
    //    (exact resync every 16 steps bounds drift to ~1e-4)
    //  - |z| <= 20                -> sigz well-conditioned
    const bool shared = (prm[11] == prm[19]) && (prm[12] == prm[20]) &&
                        (prm[15] == prm[23]) && (prm[16] == prm[24]);
    const float capx = prm[0], capy = prm[1];
    const bool gpos = prm[2] >= 0.f && prm[6] >= 0.f && prm[10] >= 0.f &&
                      prm[14] >= 0.f && prm[18] >= 0.f && prm[22] >= 0.f &&
                      capx > 0.f && capy > 0.f;
    const float sx = (prm[2] + prm[14] + prm[18]) / capx;
    const float sy = (prm[6] + prm[10] + prm[22]) / capy;
    const float lox = fminf(0.f, fminf(prm[5], fminf(prm[17], prm[21])));
    const float hix = fmaxf(0.f, fmaxf(prm[5], fmaxf(prm[17], prm[21])));
    const float loy = fminf(1.f, fminf(prm[9], fminf(prm[13], prm[25])));
    const float hiy = fmaxf(1.f, fmaxf(prm[9], fmaxf(prm[13], prm[25])));
    const float wbx = prm[20] * sx * (hix - lox), wby = prm[24] * sy * (hiy - loy);
    const float zmx = prm[20] * fmaxf(fabsf(lox - prm[19]), fabsf(hix - prm[19]));
    const float zmy = prm[24] * fmaxf(fabsf(loy - prm[23]), fabsf(hiy - prm[23]));
    const bool fast = shared && gpos && sx <= 0.25f && sy <= 0.25f &&
                      wbx <= 0.02f && wby <= 0.02f && zmx <= 20.f && zmy <= 20.f;
    if (fast) {
        run_fast(inp, prm, out, sgbuf, st);
    } else {
        run_exact(inp, prm, out);
    }
}

extern "C" void kernel_launch(void* const* d_in, const int* in_sizes, int n_in,
                              void* d_out, int out_size, void* d_ws, size_t ws_size,
                              hipStream_t stream) {
    (void)in_sizes; (void)n_in; (void)d_ws; (void)ws_size; (void)out_size;
    const float* inp = (const float*)d_in[0];
    const float* prm = (const float*)d_in[1];
    float* out = (float*)d_out;
    memcell_scan<<<dim3(NROWS / RPB), dim3(128), 0, stream>>>(inp, prm, out);
}

// Round 13
// 317.441 us; speedup vs baseline: 1.2462x; 1.2459x over previous
//
#include <hip/hip_runtime.h>

#define TLEN  4096
#define NROWS 4096
#define RPB   32            // rows per block (owned by the scan wave)
#define K     32            // timesteps per chunk
#define NC    (TLEN / K)    // 128 chunks
#define LDPAD 66            // staged-output row pitch (dwords): 64 data + 2 pad
#define SGSL  (16 * 32)     // sgin slot: 16 tp-granules x 32 rows (float4 units)
#define STSL  (RPB * LDPAD) // output-staging slot (floats)
#define UN    8             // exact-path unroll

__device__ __forceinline__ float fexp2(float x) { return __builtin_amdgcn_exp2f(x); }
__device__ __forceinline__ float frcp(float x)  { return __builtin_amdgcn_rcpf(x); }
__device__ __forceinline__ float sigz(float z)  { return frcp(1.0f + fexp2(z)); }

// Swap adjacent lanes (lane ^ 1): DPP quad_perm [1,0,3,2].
__device__ __forceinline__ float lane_swap1(float v) {
    int r = __builtin_amdgcn_update_dpp(0, __float_as_int(v), 0xB1, 0xF, 0xF, true);
    return __int_as_float(r);
}

// ---------------------------------------------------------------------------
// Round-12 resubmission (r12 bench was an infra acquisition failure; no
// dispatch ran). = round-9 VERBATIM (184us, best verified) with the helper
// split across two waves (r11's pre-registered action). No scan changes.
//   wave 0 (scan):    r9 scan byte-for-byte (measured 108 cyc/step -- the
//                     lean-compiled artifact; r10/r11 rewrites compiled fat).
//   wave 1 (produce): r9's register-prefetch + sigmoid produce. Loads for
//                     chunk c+2 are issued BEFORE producing c+1, so the
//                     barrier's vmcnt drain sees mostly-absorbed latency.
//   wave 2 (flush):   r9's flush verbatim (chunk c-1 -> HBM).
// All three waves execute exactly 1 + NC __syncthreads (prologue + per
// chunk); flush epilogue after the loop. Clean A/B on "was r9's helper
// marginally the pole": helper streams drop to ~1500 / ~1000 cyc vs the
// combined ~2500+, scan untouched.
// ---------------------------------------------------------------------------
__device__ void run_fast(const float* __restrict__ inp, const float* __restrict__ prm,
                         float* __restrict__ out,
                         float4* __restrict__ sgbuf,  // [2][16 tp][32 row] float4
                         float*  __restrict__ st) {   // [2][RPB][LDPAD]
    const int tid  = threadIdx.x;
    const int wid  = tid >> 6;          // 0 = scan, 1 = produce, 2 = flush
    const int lane = tid & 63;
    const int R0   = blockIdx.x * RPB;
    const float L2E = 1.4426950408889634f;
    float2* __restrict__ out2 = (float2*)out;

    if (wid == 1) {
        // ---------------- produce wave ----------------
        const int r = lane & 31, h = lane >> 5;
        // input-sigmoid constants: 'ax' dir for x (base 2), 'by' dir for y (base 6)
        const float c1x = -prm[4] * L2E, c0x = prm[4] * prm[3] * L2E;
        const float c1y = -prm[8] * L2E, c0y = prm[8] * prm[7] * L2E;
        const float4* __restrict__ src = (const float4*)inp + (size_t)(R0 + r) * (TLEN / 2);

        float4 bufA[8], bufB[8];

        auto produce_reg = [&](const float4* buf, int c) {  // regs -> sgbuf slot c&1
            float4* sl = sgbuf + ((c & 1) ? SGSL : 0);
#pragma unroll
            for (int j = 0; j < 8; ++j) {
                float4 v = buf[j];            // (a_t, b_t, a_t+1, b_t+1)
                float4 o;
                o.x = sigz(__builtin_fmaf(c1x, v.x, c0x));
                o.y = sigz(__builtin_fmaf(c1y, v.y, c0y));
                o.z = sigz(__builtin_fmaf(c1x, v.z, c0x));
                o.w = sigz(__builtin_fmaf(c1y, v.w, c0y));
                sl[(h * 8 + j) * 32 + r] = o;   // same layout scan's ds_read expects
            }
        };

        // prologue: chunk 0 -> bufA -> produce; chunk 1 -> bufB (in flight)
#pragma unroll
        for (int j = 0; j < 8; ++j) bufA[j] = src[h * 8 + j];
        produce_reg(bufA, 0);
#pragma unroll
        for (int j = 0; j < 8; ++j) bufB[j] = src[16 + h * 8 + j];
        __syncthreads();                       // slot 0 ready for scan
        for (int c = 0; c < NC; ++c) {
            // issue next prefetch FIRST so its latency hides under produce
            if ((c & 1) == 0) {
                if (c + 2 < NC) {
#pragma unroll
                    for (int j = 0; j < 8; ++j)
                        bufA[j] = src[(c + 2) * 16 + h * 8 + j];
                }
                if (c + 1 < NC) produce_reg(bufB, c + 1);   // chunk c+1 (odd)
            } else {
                if (c + 2 < NC) {
#pragma unroll
                    for (int j = 0; j < 8; ++j)
                        bufB[j] = src[(c + 2) * 16 + h * 8 + j];
                }
                if (c + 1 < NC) produce_reg(bufA, c + 1);   // chunk c+1 (even)
            }
            __syncthreads();
        }
    } else if (wid == 2) {
        // ---------------- flush wave ----------------
        auto flush = [&](int c) {     // st slot c&1 -> out, 256B coalesced runs
            const float* sl = st + ((c & 1) ? STSL : 0);
            const int col = lane & 31;
#pragma unroll
            for (int j = 0; j < 16; ++j) {
                int ro = 2 * j + (lane >> 5);
                float2 v = *(const float2*)&sl[ro * LDPAD + col * 2];
                out2[(size_t)(R0 + ro) * TLEN + (size_t)c * K + col] = v;
            }
        };

        __syncthreads();
        for (int c = 0; c < NC; ++c) {
            if (c >= 1) flush(c - 1);          // previous chunk's outputs
            __syncthreads();
        }
        flush(NC - 1);                         // epilogue: last chunk's outputs
    } else {
        // ---------------- scan wave (r9 verbatim) ----------------
        // Lane pair (2r, 2r+1) owns row r: even lane = x, odd = y.
        const int r_  = lane >> 1;
        const int par = lane & 1;
        const int inB = par ? 6 : 2, sfB = par ? 22 : 18, t2B = par ? 10 : 14;
        const float ic  = 1.0f / prm[par];
        const float g1  = prm[sfB] * ic, P1 = g1 * prm[sfB + 3], Gn1 = -g1; // self
        const float g2  = prm[t2B] * ic, P2 = g2 * prm[t2B + 3], Gn2 = -g2; // cross
        const float gA  = prm[inB] * ic, PA = gA * prm[inB + 3], GnA = -gA; // input
        const float sdz = prm[sfB + 2];
        const float c1s = -sdz * L2E, c0s = sdz * prm[sfB + 1] * L2E;

        float x   = par ? 1.0f : 0.0f;
        float sig = sigz(__builtin_fmaf(c1s, x, c0s));
        float u   = __builtin_fmaf(-sig, sig, sig);   // sig*(1-sig)

        auto resync = [&]() {                         // exact sigma (off-chain)
            sig = sigz(__builtin_fmaf(c1s, x, c0s));
            u   = __builtin_fmaf(-sig, sig, sig);
        };

        auto step = [&](float sg, float* wp, int t) {
            float Av  = __builtin_fmaf(GnA, x, PA);
            float t1v = __builtin_fmaf(Gn1, x, P1);
            float t2v = __builtin_fmaf(Gn2, x, P2);
            float m   = sg * Av;                      // sgin precomputed by helper
            float b2  = __builtin_fmaf(sig, t1v, m);
            float sc  = lane_swap1(sig);              // partner's sigma
            float dx  = __builtin_fmaf(sc, t2v, b2);
            x = x + dx;
            wp[2 * t] = x;                            // ds_write_b32, imm offset
            float dz = sdz * dx;
            sig = __builtin_fmaf(u, dz, sig);         // deg-1 Taylor
            u   = __builtin_fmaf(-sig, sig, sig);
        };

        __syncthreads();                       // sgbuf slot 0 ready
        for (int c = 0; c < NC; ++c) {
            const float4* lb = sgbuf + ((c & 1) ? SGSL : 0);
            float* wp = st + ((c & 1) ? STSL : 0) + r_ * LDPAD + par;
            float4 f0 = lb[r_];
            float4 f1 = lb[32 + r_];
#pragma unroll
            for (int tp = 0; tp < 16; ++tp) {
                float4 f = f0; f0 = f1;
                if (tp < 14) f1 = lb[(tp + 2) * 32 + r_];   // 2-pair lookahead
                step(par ? f.y : f.x, wp, 2 * tp);
                step(par ? f.w : f.z, wp, 2 * tp + 1);
                if (tp == 7) resync();                      // mid-chunk resync
            }
            resync();                                       // end-chunk resync
            __syncthreads();                   // hand slots to helpers / get next
        }
    }
}

// ---------------------------------------------------------------------------
// Exact fallback for general params (proven path; 192-thr blocks, threads
// beyond row 4095 idle).
// ---------------------------------------------------------------------------
struct LaneConst {
    float c1_in, c0_in, c1_sf, c0_sf, c1_ot, c0_ot;
    float gS_in, gS_cr, gS_sf, gP_in, gP_cr, gP_sf;
};

__device__ __forceinline__ float do_step_exact(float s, float pre_in, const LaneConst& k) {
    float sig_in = sigz(__builtin_fmaf(k.c1_in, pre_in, k.c0_in));
    float sig_sf = sigz(__builtin_fmaf(k.c1_sf, s, k.c0_sf));
    float sig_ot = sigz(__builtin_fmaf(k.c1_ot, s, k.c0_ot));
    float sig_cr = lane_swap1(sig_ot);
    float S = __builtin_fmaf(k.gS_in, sig_in, __builtin_fmaf(k.gS_cr, sig_cr, k.gS_sf * sig_sf));
    float P = __builtin_fmaf(k.gP_in, sig_in, __builtin_fmaf(k.gP_cr, sig_cr, k.gP_sf * sig_sf));
    return s + __builtin_fmaf(S, -s, P);
}

__device__ void run_exact(const float* __restrict__ inp, const float* __restrict__ prm,
                          float* __restrict__ out) {
    const int tid = blockIdx.x * 192 + threadIdx.x;
    const int row = tid >> 1;
    if (row >= NROWS) return;
    const int par = tid & 1;
    const float L2E = 1.4426950408889634f;
    const int inB = par ? 6 : 2, sfB = par ? 22 : 18, otB = par ? 14 : 10, crB = par ? 10 : 14;
    const float invc = 1.0f / prm[par];
    LaneConst k;
    float sd = prm[inB + 2], mn = prm[inB + 1];
    k.c1_in = -sd * L2E; k.c0_in = sd * mn * L2E;
    sd = prm[sfB + 2]; mn = prm[sfB + 1];
    k.c1_sf = -sd * L2E; k.c0_sf = sd * mn * L2E;
    sd = prm[otB + 2]; mn = prm[otB + 1];
    k.c1_ot = -sd * L2E; k.c0_ot = sd * mn * L2E;
    k.gS_in = prm[inB] * invc; k.gP_in = k.gS_in * prm[inB + 3];
    k.gS_sf = prm[sfB] * invc; k.gP_sf = k.gS_sf * prm[sfB + 3];
    k.gS_cr = prm[crB] * invc; k.gP_cr = k.gS_cr * prm[crB + 3];

    const float4* __restrict__ src = (const float4*)inp + (size_t)row * (TLEN / 2);
    float* __restrict__ dst = out + (size_t)row * (TLEN * 2) + par;
    float s = par ? 1.0f : 0.0f;

    float4 cur[UN], nxt[UN];
#pragma unroll
    for (int j = 0; j < UN; ++j) cur[j] = src[j];
    const int NIT = TLEN / (2 * UN);
    for (int it = 0; it < NIT; ++it) {
        if (it + 1 < NIT) {
#pragma unroll
            for (int j = 0; j < UN; ++j) nxt[j] = src[(it + 1) * UN + j];
        }
        float* dptr = dst + it * (UN * 4);
#pragma unroll
        for (int j = 0; j < UN; ++j) {
            float4 f = cur[j];
            s = do_step_exact(s, par ? f.y : f.x, k);
            dptr[j * 4] = s;
            s = do_step_exact(s, par ? f.w : f.z, k);
            dptr[j * 4 + 2] = s;
        }
#pragma unroll
        for (int j = 0; j < UN; ++j) cur[j] = nxt[j];
    }
}

__global__ __launch_bounds__(192, 1)
void memcell_scan(const float* __restrict__ inp, const float* __restrict__ prm,
                  float* __restrict__ out) {
    __shared__ float4 sgbuf[2 * SGSL];   // 16 KB sgin double-buffer
    __shared__ float  st[2 * STSL];      // 16.9 KB output staging double-buffer

    // Fast-path guard:
    //  - shared (mean,std) between self & cross state dirs (xx==xy, yy==yx)
    //  - g >= 0, caps > 0         -> states stay in hull{s0, pots}
    //  - sum(g/cap) <= 0.25       -> no overshoot
    //  - wb = std*max|dx| <= 0.02 -> deg-1 sigma-Taylor valid
    //    (exact resync every 16 steps bounds drift to ~1e-4)
    //  - |z| <= 20                -> sigz well-conditioned
    const bool shared = (prm[11] == prm[19]) && (prm[12] == prm[20]) &&
                        (prm[15] == prm[23]) && (prm[16] == prm[24]);
    const float capx = prm[0], capy = prm[1];
    const bool gpos = prm[2] >= 0.f && prm[6] >= 0.f && prm[10] >= 0.f &&
                      prm[14] >= 0.f && prm[18] >= 0.f && prm[22] >= 0.f &&
                      capx > 0.f && capy > 0.f;
    const float sx = (prm[2] + prm[14] + prm[18]) / capx;
    const float sy = (prm[6] + prm[10] + prm[22]) / capy;
    const float lox = fminf(0.f, fminf(prm[5], fminf(prm[17], prm[21])));
    const float hix = fmaxf(0.f, fmaxf(prm[5], fmaxf(prm[17], prm[21])));
    const float loy = fminf(1.f, fminf(prm[9], fminf(prm[13], prm[25])));
    const float hiy = fmaxf(1.f, fmaxf(prm[9], fmaxf(prm[13], prm[25])));
    const float wbx = prm[20] * sx * (hix - lox), wby = prm[24] * sy * (hiy - loy);
    const float zmx = prm[20] * fmaxf(fabsf(lox - prm[19]), fabsf(hix - prm[19]));
    const float zmy = prm[24] * fmaxf(fabsf(loy - prm[23]), fabsf(hiy - prm[23]));
    const bool fast = shared && gpos && sx <= 0.25f && sy <= 0.25f &&
                      wbx <= 0.02f && wby <= 0.02f && zmx <= 20.f && zmy <= 20.f;
    if (fast) {
        run_fast(inp, prm, out, sgbuf, st);
    } else {
        run_exact(inp, prm, out);
    }
}

extern "C" void kernel_launch(void* const* d_in, const int* in_sizes, int n_in,
                              void* d_out, int out_size, void* d_ws, size_t ws_size,
                              hipStream_t stream) {
    (void)in_sizes; (void)n_in; (void)d_ws; (void)ws_size; (void)out_size;
    const float* inp = (const float*)d_in[0];
    const float* prm = (const float*)d_in[1];
    float* out = (float*)d_out;
    memcell_scan<<<dim3(NROWS / RPB), dim3(192), 0, stream>>>(inp, prm, out);
}